// Round 1
// baseline (455.501 us; speedup 1.0000x reference)
//
#include <hip/hip_runtime.h>

#define BATCH 64
#define CDIM 256
#define HW   1024          // 32*32 pixels per batch image
#define NPIX 65536         // 64*1024
#define KDIM 1024          // num_emb
#define TILE_N 128
#define TILE_K 128
#define CB   16

// -------- kernel A: ee[k] = sum_c embed[c][k]^2 --------
__global__ void ee_kernel(const float* __restrict__ embed, float* __restrict__ ee) {
    int k = blockIdx.x * 256 + threadIdx.x;
    float s = 0.f;
#pragma unroll 8
    for (int c = 0; c < CDIM; ++c) {
        float v = embed[c * KDIM + k];
        s += v * v;
    }
    ee[k] = s;
}

// -------- kernel B: distances + argmin + gather + writeback + loss partials --------
__launch_bounds__(256)
__global__ void vq_main(const float* __restrict__ x, const float* __restrict__ embed,
                        const float* __restrict__ ee, float* __restrict__ out_q,
                        float* __restrict__ out_idx, float* __restrict__ partials) {
    __shared__ float As[CB][TILE_N];
    __shared__ float Bs[CB][TILE_K];
    __shared__ float ees[KDIM];
    __shared__ float redv[TILE_N][16];
    __shared__ int   redi[TILE_N][16];
    __shared__ int   idxs[TILE_N];
    __shared__ float lred[4];

    const int t  = threadIdx.x;
    const int tx = t & 15;
    const int ty = t >> 4;

    const int n0   = blockIdx.x * TILE_N;     // global pixel base
    const int b    = n0 >> 10;
    const int pix0 = n0 & 1023;
    const long xbase = (long)b * CDIM * HW + pix0;

    // stage ee into LDS
#pragma unroll
    for (int i = 0; i < 4; ++i) ees[t + i * 256] = ee[t + i * 256];

    float minv[8];
    int   mini[8];
#pragma unroll
    for (int r = 0; r < 8; ++r) { minv[r] = 3.4e38f; mini[r] = 0; }

    // loader mapping: 8 rows of 128 floats each, via float4
    const int lcc  = t >> 5;         // 0..7
    const int lcol = (t & 31) * 4;   // 0..124

    for (int kt = 0; kt < KDIM / TILE_K; ++kt) {
        const int k0 = kt * TILE_K;
        float acc[8][8];
#pragma unroll
        for (int r = 0; r < 8; ++r)
#pragma unroll
            for (int c = 0; c < 8; ++c) acc[r][c] = 0.f;

        for (int c0 = 0; c0 < CDIM; c0 += CB) {
            __syncthreads();   // previous compute done before overwriting As/Bs
            float4 av0 = *(const float4*)&x[xbase + (long)(c0 + lcc) * HW + lcol];
            float4 av1 = *(const float4*)&x[xbase + (long)(c0 + lcc + 8) * HW + lcol];
            float4 bv0 = *(const float4*)&embed[(c0 + lcc) * KDIM + k0 + lcol];
            float4 bv1 = *(const float4*)&embed[(c0 + lcc + 8) * KDIM + k0 + lcol];
            *(float4*)&As[lcc][lcol]     = av0;
            *(float4*)&As[lcc + 8][lcol] = av1;
            *(float4*)&Bs[lcc][lcol]     = bv0;
            *(float4*)&Bs[lcc + 8][lcol] = bv1;
            __syncthreads();

#pragma unroll
            for (int cc = 0; cc < CB; ++cc) {
                float4 a0 = *(const float4*)&As[cc][ty * 4];
                float4 a1 = *(const float4*)&As[cc][64 + ty * 4];
                float4 b0 = *(const float4*)&Bs[cc][tx * 4];
                float4 b1 = *(const float4*)&Bs[cc][64 + tx * 4];
                float ar[8] = {a0.x, a0.y, a0.z, a0.w, a1.x, a1.y, a1.z, a1.w};
                float br[8] = {b0.x, b0.y, b0.z, b0.w, b1.x, b1.y, b1.z, b1.w};
#pragma unroll
                for (int r = 0; r < 8; ++r)
#pragma unroll
                    for (int c = 0; c < 8; ++c)
                        acc[r][c] = fmaf(ar[r], br[c], acc[r][c]);
            }
        }

        // fold this code tile into running argmin
#pragma unroll
        for (int c = 0; c < 8; ++c) {
            const int kg = k0 + ((c & 4) * 16) + tx * 4 + (c & 3);
            const float eev = ees[kg];
#pragma unroll
            for (int r = 0; r < 8; ++r) {
                float m = fmaf(-2.f, acc[r][c], eev);
                if (m < minv[r] || (m == minv[r] && kg < mini[r])) {
                    minv[r] = m; mini[r] = kg;
                }
            }
        }
    }

    // cross-thread argmin reduce: rows handled by the 16 tx threads
#pragma unroll
    for (int r = 0; r < 8; ++r) {
        const int row = ((r & 4) * 16) + ty * 4 + (r & 3);
        redv[row][tx] = minv[r];
        redi[row][tx] = mini[r];
    }
    __syncthreads();
    if (t < TILE_N) {
        float bv = redv[t][0];
        int   bi = redi[t][0];
#pragma unroll
        for (int j = 1; j < 16; ++j) {
            float v = redv[t][j]; int i = redi[t][j];
            if (v < bv || (v == bv && i < bi)) { bv = v; bi = i; }
        }
        idxs[t] = bi;
        out_idx[n0 + t] = (float)bi;
    }
    __syncthreads();

    // gather + writeback + loss partial
    float lsum = 0.f;
    const int lp = t & 127;
    const int lc = t >> 7;          // 0 or 1
    const long obase = xbase;
    const int myidx = idxs[lp];
    for (int c = lc; c < CDIM; c += 2) {
        float q  = embed[c * KDIM + myidx];
        float xv = x[xbase + (long)c * HW + lp];
        out_q[obase + (long)c * HW + lp] = q;
        float d = q - xv;
        lsum = fmaf(d, d, lsum);
    }
    // deterministic block reduce: wave shuffle then 4-entry LDS
#pragma unroll
    for (int off = 32; off > 0; off >>= 1)
        lsum += __shfl_down(lsum, off, 64);
    if ((t & 63) == 0) lred[t >> 6] = lsum;
    __syncthreads();
    if (t == 0)
        partials[blockIdx.x] = (lred[0] + lred[1]) + (lred[2] + lred[3]);
}

// -------- kernel C: final loss reduce --------
__global__ void loss_kernel(const float* __restrict__ partials, float* __restrict__ out_loss) {
    __shared__ float s[256];
    s[threadIdx.x] = partials[threadIdx.x] + partials[threadIdx.x + 256];
    __syncthreads();
    for (int off = 128; off > 0; off >>= 1) {
        if (threadIdx.x < off) s[threadIdx.x] += s[threadIdx.x + off];
        __syncthreads();
    }
    if (threadIdx.x == 0)
        out_loss[0] = 1.25f * s[0] / 16777216.0f;
}

extern "C" void kernel_launch(void* const* d_in, const int* in_sizes, int n_in,
                              void* d_out, int out_size, void* d_ws, size_t ws_size,
                              hipStream_t stream) {
    const float* x     = (const float*)d_in[0];
    const float* embed = (const float*)d_in[1];
    float* out_q    = (float*)d_out;
    float* out_loss = out_q + (long)NPIX * CDIM;   // 16777216
    float* out_idx  = out_loss + 1;
    float* ws       = (float*)d_ws;
    float* ee       = ws;            // 1024 floats
    float* partials = ws + 1024;     // 512 floats

    ee_kernel<<<KDIM / 256, 256, 0, stream>>>(embed, ee);
    vq_main<<<NPIX / TILE_N, 256, 0, stream>>>(x, embed, ee, out_q, out_idx, partials);
    loss_kernel<<<1, 256, 0, stream>>>(partials, out_loss);
}

// Round 2
// 446.792 us; speedup vs baseline: 1.0195x; 1.0195x over previous
//
#include <hip/hip_runtime.h>

#define CDIM 256
#define HW   1024
#define NPIX 65536
#define KDIM 1024
#define TAU  0.0625f

using bf16x8 = __attribute__((ext_vector_type(8))) short;
using f32x4  = __attribute__((ext_vector_type(4))) float;

static __device__ inline unsigned short f2bf(float v) {
    union { float f; unsigned u; } a; a.f = v;
    unsigned u = a.u;
    u += 0x7fffu + ((u >> 16) & 1u);   // RTN
    return (unsigned short)(u >> 16);
}
static __device__ inline float bf2f(unsigned short h) {
    union { unsigned u; float f; } a; a.u = ((unsigned)h) << 16;
    return a.f;
}

// -------- ee[k] = sum_c embed[c][k]^2 (exact fp32) --------
__global__ void ee_kernel(const float* __restrict__ embed, float* __restrict__ ee) {
    int k = blockIdx.x * 256 + threadIdx.x;
    float s = 0.f;
#pragma unroll 8
    for (int c = 0; c < CDIM; ++c) {
        float v = embed[c * KDIM + k];
        s += v * v;
    }
    ee[k] = s;
}

// -------- split -2*embed into bf16 hi/lo, swizzled into MFMA B-fragment order --------
// frag f = ((nt*8 + ks)*8 + nfg), lane l: element j (0..7) is
//   B[k = ks*32 + (l>>4)*8 + j][n = nt*128 + nfg*16 + (l&15)]
// stored at (f*64 + l)*8 + j.
__global__ void prep_kernel(const float* __restrict__ embed,
                            short* __restrict__ e_hi, short* __restrict__ e_lo) {
    int tid = blockIdx.x * 256 + threadIdx.x;   // 36864 total
    int l   = tid & 63;
    int f   = tid >> 6;
    int nfg = f & 7;
    int ks  = (f >> 3) & 7;
    int nt  = f >> 6;
    int n   = nt * 128 + nfg * 16 + (l & 15);
    int c0  = ks * 32 + (l >> 4) * 8;
    bf16x8 h8, l8;
#pragma unroll
    for (int j = 0; j < 8; ++j) {
        float v = -2.0f * embed[(c0 + j) * KDIM + n];
        unsigned short h = f2bf(v);
        unsigned short lo = f2bf(v - bf2f(h));
        h8[j] = (short)h;
        l8[j] = (short)lo;
    }
    *(bf16x8*)&e_hi[(size_t)tid * 8] = h8;
    *(bf16x8*)&e_lo[(size_t)tid * 8] = l8;
}

// -------- main: split-bf16 MFMA distances + running argmin + gap flagging --------
__launch_bounds__(256)
__global__ void vq_mfma(const float* __restrict__ x,
                        const short* __restrict__ e_hi, const short* __restrict__ e_lo,
                        const float* __restrict__ ee,
                        int* __restrict__ idx_out,
                        int* __restrict__ worklist, int* __restrict__ wcount) {
    __shared__ float ees[KDIM];
    const int t = threadIdx.x;
    const int l = t & 63;
    const int w = t >> 6;
    const int lr = l & 15;      // frag row/col
    const int lg = l >> 4;      // k-group

    const int n0 = blockIdx.x * 128;
    const int b  = n0 >> 10;
    const int p0 = (n0 & 1023) + w * 32;
    const float* xw = x + (size_t)b * CDIM * HW + p0;

#pragma unroll
    for (int i = 0; i < 4; ++i) ees[t + i * 256] = ee[t + i * 256];
    __syncthreads();

    // ---- load A fragments (32 pixels x 256 ch), convert to bf16 hi/lo ----
    bf16x8 ahi[2][8], alo[2][8];
#pragma unroll
    for (int mf = 0; mf < 2; ++mf) {
#pragma unroll
        for (int ks = 0; ks < 8; ++ks) {
            const float* px = xw + (size_t)(ks * 32 + lg * 8) * HW + mf * 16 + lr;
            float v[8];
#pragma unroll
            for (int j = 0; j < 8; ++j) v[j] = px[(size_t)j * HW];
#pragma unroll
            for (int j = 0; j < 8; ++j) {
                unsigned short h = f2bf(v[j]);
                unsigned short lo = f2bf(v[j] - bf2f(h));
                ahi[mf][ks][j] = (short)h;
                alo[mf][ks][j] = (short)lo;
            }
        }
    }

    float minv[8], min2v[8];
    int   mini[8];
#pragma unroll
    for (int r = 0; r < 8; ++r) { minv[r] = 3.4e38f; min2v[r] = 3.4e38f; mini[r] = 0; }

    for (int nt = 0; nt < 8; ++nt) {
        for (int nh = 0; nh < 2; ++nh) {
            f32x4 acc[2][4];
#pragma unroll
            for (int mf = 0; mf < 2; ++mf)
#pragma unroll
                for (int nf = 0; nf < 4; ++nf)
                    acc[mf][nf] = (f32x4){0.f, 0.f, 0.f, 0.f};

#pragma unroll
            for (int ks = 0; ks < 8; ++ks) {
#pragma unroll
                for (int nf = 0; nf < 4; ++nf) {
                    size_t off = ((((size_t)nt * 8 + ks) * 8 + nh * 4 + nf) * 64 + l) * 8;
                    bf16x8 bh = *(const bf16x8*)&e_hi[off];
                    bf16x8 bl = *(const bf16x8*)&e_lo[off];
                    acc[0][nf] = __builtin_amdgcn_mfma_f32_16x16x32_bf16(ahi[0][ks], bh, acc[0][nf], 0, 0, 0);
                    acc[1][nf] = __builtin_amdgcn_mfma_f32_16x16x32_bf16(ahi[1][ks], bh, acc[1][nf], 0, 0, 0);
                    acc[0][nf] = __builtin_amdgcn_mfma_f32_16x16x32_bf16(alo[0][ks], bh, acc[0][nf], 0, 0, 0);
                    acc[1][nf] = __builtin_amdgcn_mfma_f32_16x16x32_bf16(alo[1][ks], bh, acc[1][nf], 0, 0, 0);
                    acc[0][nf] = __builtin_amdgcn_mfma_f32_16x16x32_bf16(ahi[0][ks], bl, acc[0][nf], 0, 0, 0);
                    acc[1][nf] = __builtin_amdgcn_mfma_f32_16x16x32_bf16(ahi[1][ks], bl, acc[1][nf], 0, 0, 0);
                }
            }

            // fold into running (min, argmin, second-min)
#pragma unroll
            for (int nf = 0; nf < 4; ++nf) {
                const int kg = nt * 128 + (nh * 4 + nf) * 16 + lr;
                const float eev = ees[kg];
#pragma unroll
                for (int mf = 0; mf < 2; ++mf)
#pragma unroll
                    for (int reg = 0; reg < 4; ++reg) {
                        const int r = mf * 4 + reg;
                        float m = acc[mf][nf][reg] + eev;
                        bool lt = m < minv[r];
                        float sec = lt ? minv[r] : m;
                        minv[r] = lt ? m : minv[r];
                        mini[r] = lt ? kg : mini[r];
                        min2v[r] = fminf(min2v[r], sec);
                    }
            }
        }
    }

    // ---- reduce across the 16 lanes sharing each pixel row ----
#pragma unroll
    for (int r = 0; r < 8; ++r) {
        float v1 = minv[r]; int i1 = mini[r]; float v2 = min2v[r];
#pragma unroll
        for (int mask = 1; mask < 16; mask <<= 1) {
            float ov1 = __shfl_xor(v1, mask, 64);
            int   oi1 = __shfl_xor(i1, mask, 64);
            float ov2 = __shfl_xor(v2, mask, 64);
            float vmax = fmaxf(v1, ov1);
            v2 = fminf(fminf(v2, ov2), vmax);
            bool take = (ov1 < v1) || (ov1 == v1 && oi1 < i1);
            v1 = take ? ov1 : v1;
            i1 = take ? oi1 : i1;
        }
        if (lr == 0) {
            int prow = (r >> 2) * 16 + lg * 4 + (r & 3);
            int gn = n0 + w * 32 + prow;
            idx_out[gn] = i1;
            if (v2 - v1 < TAU) {
                int pos = atomicAdd(wcount, 1);
                worklist[pos] = gn;
            }
        }
    }
}

// -------- exact fp32 rescore for flagged (near-tie) pixels --------
__global__ void vq_rescue(const float* __restrict__ x, const float* __restrict__ embed,
                          const float* __restrict__ ee,
                          const int* __restrict__ worklist, const int* __restrict__ wcount,
                          int* __restrict__ idx_out) {
    __shared__ float xs[CDIM];
    __shared__ float bv[4];
    __shared__ int   bi[4];
    const int t = threadIdx.x;
    const int cnt = *wcount;
    for (int wi = blockIdx.x; wi < cnt; wi += gridDim.x) {
        const int gn = worklist[wi];
        const int b = gn >> 10, p = gn & 1023;
        __syncthreads();
        xs[t] = x[(size_t)b * CDIM * HW + (size_t)t * HW + p];
        __syncthreads();
        float bestv = 3.4e38f; int besti = 0;
#pragma unroll
        for (int kk = 0; kk < 4; ++kk) {
            int k = t + kk * 256;
            float dot = 0.f;
            for (int c = 0; c < CDIM; ++c)
                dot = fmaf(xs[c], embed[c * KDIM + k], dot);
            float d = fmaf(-2.f, dot, ee[k]);
            if (d < bestv || (d == bestv && k < besti)) { bestv = d; besti = k; }
        }
#pragma unroll
        for (int mask = 1; mask < 64; mask <<= 1) {
            float ov = __shfl_xor(bestv, mask, 64);
            int   oi = __shfl_xor(besti, mask, 64);
            bool take = (ov < bestv) || (ov == bestv && oi < besti);
            bestv = take ? ov : bestv;
            besti = take ? oi : besti;
        }
        if ((t & 63) == 0) { bv[t >> 6] = bestv; bi[t >> 6] = besti; }
        __syncthreads();
        if (t == 0) {
            float fv = bv[0]; int fi = bi[0];
#pragma unroll
            for (int q = 1; q < 4; ++q) {
                if (bv[q] < fv || (bv[q] == fv && bi[q] < fi)) { fv = bv[q]; fi = bi[q]; }
            }
            idx_out[gn] = fi;
        }
        __syncthreads();
    }
}

// -------- epilogue: gather codebook, write quantize + idx(float) + loss partials --------
__launch_bounds__(256)
__global__ void vq_epilogue(const float* __restrict__ x, const float* __restrict__ embed,
                            const int* __restrict__ idx_in, float* __restrict__ out_q,
                            float* __restrict__ out_idx, float* __restrict__ partials) {
    __shared__ int idxs[128];
    __shared__ float lred[4];
    const int t = threadIdx.x;
    const int n0 = blockIdx.x * 128;
    const int b = n0 >> 10;
    const int pix0 = n0 & 1023;
    const size_t xbase = (size_t)b * CDIM * HW + pix0;

    if (t < 128) idxs[t] = idx_in[n0 + t];
    __syncthreads();
    if (t < 128) out_idx[n0 + t] = (float)idxs[t];

    float lsum = 0.f;
    const int lp = t & 127;
    const int lc = t >> 7;
    const int myidx = idxs[lp];
    for (int c = lc; c < CDIM; c += 2) {
        float q  = embed[c * KDIM + myidx];
        float xv = x[xbase + (size_t)c * HW + lp];
        out_q[xbase + (size_t)c * HW + lp] = q;
        float d = q - xv;
        lsum = fmaf(d, d, lsum);
    }
#pragma unroll
    for (int off = 32; off > 0; off >>= 1)
        lsum += __shfl_down(lsum, off, 64);
    if ((t & 63) == 0) lred[t >> 6] = lsum;
    __syncthreads();
    if (t == 0)
        partials[blockIdx.x] = (lred[0] + lred[1]) + (lred[2] + lred[3]);
}

__global__ void loss_kernel(const float* __restrict__ partials, float* __restrict__ out_loss) {
    __shared__ float s[256];
    s[threadIdx.x] = partials[threadIdx.x] + partials[threadIdx.x + 256];
    __syncthreads();
    for (int off = 128; off > 0; off >>= 1) {
        if (threadIdx.x < off) s[threadIdx.x] += s[threadIdx.x + off];
        __syncthreads();
    }
    if (threadIdx.x == 0)
        out_loss[0] = 1.25f * s[0] / 16777216.0f;
}

extern "C" void kernel_launch(void* const* d_in, const int* in_sizes, int n_in,
                              void* d_out, int out_size, void* d_ws, size_t ws_size,
                              hipStream_t stream) {
    const float* x     = (const float*)d_in[0];
    const float* embed = (const float*)d_in[1];
    float* out_q    = (float*)d_out;
    float* out_loss = out_q + (size_t)NPIX * CDIM;
    float* out_idx  = out_loss + 1;
    int*   idx_i32  = (int*)out_idx;              // same region, int view

    // scratch inside out_q region (epilogue overwrites it afterwards)
    short* e_hi     = (short*)out_q;              // 524288 shorts = 1 MB
    short* e_lo     = e_hi + 524288;              // 1 MB
    int*   worklist = (int*)(out_q + 524288);     // 65536 ints

    float* ws       = (float*)d_ws;
    float* ee       = ws;                         // 1024 floats
    int*   wcount   = (int*)(ws + 1024);
    float* partials = ws + 1024 + 64;             // 512 floats

    ee_kernel<<<KDIM / 256, 256, 0, stream>>>(embed, ee);
    prep_kernel<<<144, 256, 0, stream>>>(embed, e_hi, e_lo);
    hipMemsetAsync(wcount, 0, 4, stream);
    vq_mfma<<<NPIX / 128, 256, 0, stream>>>(x, e_hi, e_lo, ee, idx_i32, worklist, wcount);
    vq_rescue<<<192, 256, 0, stream>>>(x, embed, ee, worklist, wcount, idx_i32);
    vq_epilogue<<<NPIX / 128, 256, 0, stream>>>(x, embed, idx_i32, out_q, out_idx, partials);
    loss_kernel<<<1, 256, 0, stream>>>(partials, out_loss);
}

// Round 3
// 423.141 us; speedup vs baseline: 1.0765x; 1.0559x over previous
//
#include <hip/hip_runtime.h>

#define CDIM 256
#define HW   1024
#define NPIX 65536
#define KDIM 1024
#define TAU  0.5f
#define RB   16

using bf16x8 = __attribute__((ext_vector_type(8))) short;
using f32x4  = __attribute__((ext_vector_type(4))) float;
typedef unsigned int u32;

static __device__ __forceinline__ unsigned short f2bf(float v) {
    union { float f; unsigned u; } a; a.f = v;
    unsigned u = a.u;
    u += 0x7fffu + ((u >> 16) & 1u);   // RTN
    return (unsigned short)(u >> 16);
}

static __device__ __forceinline__ void gload_lds16(const void* g, void* s) {
    __builtin_amdgcn_global_load_lds(
        (const __attribute__((address_space(1))) u32*)g,
        (__attribute__((address_space(3))) u32*)s,
        16, 0, 0);
}

// -------- ee[k] = sum_c embed[c][k]^2 (exact fp32) --------
__global__ void ee_kernel(const float* __restrict__ embed, float* __restrict__ ee) {
    int k = blockIdx.x * 256 + threadIdx.x;
    float s = 0.f;
#pragma unroll 8
    for (int c = 0; c < CDIM; ++c) {
        float v = embed[c * KDIM + k];
        s += v * v;
    }
    ee[k] = s;
}

// -------- bf16(-2*embed) in MFMA B-fragment order, chunk-contiguous --------
// frag f = ((nt*2+nh)*8 + ks)*4 + nf; lane l elem j:
//   B[k = ks*32 + (l>>4)*8 + j][n = nt*128 + (nh*4+nf)*16 + (l&15)]
__global__ void prep_e(const float* __restrict__ embed, short* __restrict__ e_hi) {
    int tid = blockIdx.x * 256 + threadIdx.x;   // 32768
    int l  = tid & 63;
    int f  = tid >> 6;            // 0..511
    int nf = f & 3;
    int ks = (f >> 2) & 7;
    int nh = (f >> 5) & 1;
    int nt = f >> 6;
    int n  = nt * 128 + (nh * 4 + nf) * 16 + (l & 15);
    int c0 = ks * 32 + (l >> 4) * 8;
    bf16x8 h8;
#pragma unroll
    for (int j = 0; j < 8; ++j)
        h8[j] = (short)f2bf(-2.0f * embed[(c0 + j) * KDIM + n]);
    *(bf16x8*)&e_hi[(size_t)tid * 8] = h8;
}

// -------- main: bf16 MFMA screen + argmin/min2 + near-tie flagging --------
__launch_bounds__(256, 1)
__global__ void vq_gemm(const float* __restrict__ x, const short* __restrict__ e_hi,
                        const float* __restrict__ ee, int* __restrict__ idx_out,
                        int* __restrict__ worklist, int* __restrict__ wcount) {
    __shared__ short Bs[2][16384];   // 2 x 32 KB chunks
    const int t  = threadIdx.x;
    const int l  = t & 63;
    const int w  = t >> 6;
    const int lr = l & 15;
    const int lg = l >> 4;
    const int px0 = blockIdx.x * 256 + w * 64;   // wave's 64 pixels
    const int b   = px0 >> 10;
    const int p0  = px0 & 1023;
    const float* xb = x + (size_t)b * CDIM * HW;

    // ---- load + convert A fragments (64 px x 256 ch -> 32 frags) ----
    bf16x8 a[4][8];
#pragma unroll
    for (int mf = 0; mf < 4; ++mf) {
#pragma unroll
        for (int ks = 0; ks < 8; ++ks) {
            const float* p = xb + (size_t)(ks * 32 + lg * 8) * HW + p0 + mf * 16 + lr;
            float v[8];
#pragma unroll
            for (int j = 0; j < 8; ++j) v[j] = p[(size_t)j * HW];
#pragma unroll
            for (int j = 0; j < 8; ++j) a[mf][ks][j] = (short)f2bf(v[j]);
        }
    }

    float minv[16], min2v[16];
    int   mini[16];
#pragma unroll
    for (int r = 0; r < 16; ++r) { minv[r] = 3.4e38f; min2v[r] = 3.4e38f; mini[r] = 0; }

    // prologue: stage chunk 0
    {
        const char* src = (const char*)e_hi + w * 8192 + l * 16;
        char* dst = (char*)&Bs[0][0] + w * 8192;
#pragma unroll
        for (int i = 0; i < 8; ++i)
            gload_lds16(src + i * 1024, dst + i * 1024);
    }
    __syncthreads();

    for (int ch = 0; ch < 16; ++ch) {
        const int cur = ch & 1;
        if (ch < 15) {   // issue next-chunk stage before compute (T3 minimum)
            const char* src = (const char*)e_hi + (size_t)(ch + 1) * 32768 + w * 8192 + l * 16;
            char* dst = (char*)&Bs[cur ^ 1][0] + w * 8192;
#pragma unroll
            for (int i = 0; i < 8; ++i)
                gload_lds16(src + i * 1024, dst + i * 1024);
        }

        f32x4 acc[4][4];
#pragma unroll
        for (int mf = 0; mf < 4; ++mf)
#pragma unroll
            for (int nf = 0; nf < 4; ++nf)
                acc[mf][nf] = (f32x4){0.f, 0.f, 0.f, 0.f};

#pragma unroll
        for (int ks = 0; ks < 8; ++ks) {
#pragma unroll
            for (int nf = 0; nf < 4; ++nf) {
                bf16x8 bh = *(const bf16x8*)&Bs[cur][((ks * 4 + nf) * 64 + l) * 8];
#pragma unroll
                for (int mf = 0; mf < 4; ++mf)
                    acc[mf][nf] = __builtin_amdgcn_mfma_f32_16x16x32_bf16(a[mf][ks], bh, acc[mf][nf], 0, 0, 0);
            }
        }

        // fold chunk into running (min, argmin, second-min)
#pragma unroll
        for (int nf = 0; nf < 4; ++nf) {
            const int kg = ch * 64 + nf * 16 + lr;
            const float eev = ee[kg];
#pragma unroll
            for (int mf = 0; mf < 4; ++mf)
#pragma unroll
                for (int j = 0; j < 4; ++j) {
                    const int r = mf * 4 + j;
                    float m = acc[mf][nf][j] + eev;
                    bool lt = m < minv[r];
                    float sec = lt ? minv[r] : m;
                    minv[r] = lt ? m : minv[r];
                    mini[r] = lt ? kg : mini[r];
                    min2v[r] = fminf(min2v[r], sec);
                }
        }
        __syncthreads();   // drains stage vmcnt + protects buffer swap
    }

    // ---- reduce across the 16 lanes sharing each pixel row ----
#pragma unroll
    for (int r = 0; r < 16; ++r) {
        float v1 = minv[r]; int i1 = mini[r]; float v2 = min2v[r];
#pragma unroll
        for (int mask = 1; mask < 16; mask <<= 1) {
            float ov1 = __shfl_xor(v1, mask, 64);
            int   oi1 = __shfl_xor(i1, mask, 64);
            float ov2 = __shfl_xor(v2, mask, 64);
            float vmax = fmaxf(v1, ov1);
            v2 = fminf(fminf(v2, ov2), vmax);
            bool take = (ov1 < v1) || (ov1 == v1 && oi1 < i1);
            v1 = take ? ov1 : v1;
            i1 = take ? oi1 : i1;
        }
        if (lr == 0) {
            int px = px0 + (r >> 2) * 16 + lg * 4 + (r & 3);
            idx_out[px] = i1;
            if (v2 - v1 < TAU) {
                int pos = atomicAdd(wcount, 1);
                worklist[pos] = px;
            }
        }
    }
}

// -------- exact fp32 rescore, 16 pixels per block pass --------
__launch_bounds__(256)
__global__ void vq_rescue(const float* __restrict__ x, const float* __restrict__ embed,
                          const float* __restrict__ ee,
                          const int* __restrict__ worklist, const int* __restrict__ wcount,
                          int* __restrict__ idx_out) {
    __shared__ float xs[RB][CDIM];
    __shared__ int   pxs[RB];
    __shared__ float redv[4][RB];
    __shared__ int   redi[4][RB];
    const int t  = threadIdx.x;
    const int wv = t >> 6, ln = t & 63;
    const int cnt = *wcount;
    for (int base = blockIdx.x * RB; base < cnt; base += gridDim.x * RB) {
        const int nb = min(RB, cnt - base);
        __syncthreads();
        if (t < RB) pxs[t] = worklist[base + (t < nb ? t : nb - 1)];
        __syncthreads();
#pragma unroll
        for (int i = 0; i < RB; ++i) {
            int gn = pxs[i];
            xs[i][t] = x[(size_t)(gn >> 10) * CDIM * HW + (size_t)t * HW + (gn & 1023)];
        }
        __syncthreads();
        float bv[RB]; int bix[RB];
#pragma unroll
        for (int i = 0; i < RB; ++i) { bv[i] = 3.4e38f; bix[i] = 0; }
        for (int kk = 0; kk < 4; ++kk) {
            const int k = kk * 256 + t;
            float acc[RB];
#pragma unroll
            for (int i = 0; i < RB; ++i) acc[i] = 0.f;
#pragma unroll 4
            for (int c = 0; c < CDIM; ++c) {
                float ev = embed[c * KDIM + k];
#pragma unroll
                for (int i = 0; i < RB; ++i) acc[i] = fmaf(xs[i][c], ev, acc[i]);
            }
            const float eek = ee[k];
#pragma unroll
            for (int i = 0; i < RB; ++i) {
                float d = fmaf(-2.f, acc[i], eek);
                if (d < bv[i] || (d == bv[i] && k < bix[i])) { bv[i] = d; bix[i] = k; }
            }
        }
#pragma unroll
        for (int i = 0; i < RB; ++i) {
            float v = bv[i]; int ix = bix[i];
#pragma unroll
            for (int mask = 1; mask < 64; mask <<= 1) {
                float ov = __shfl_xor(v, mask, 64);
                int   oi = __shfl_xor(ix, mask, 64);
                bool take = (ov < v) || (ov == v && oi < ix);
                v = take ? ov : v; ix = take ? oi : ix;
            }
            if (ln == 0) { redv[wv][i] = v; redi[wv][i] = ix; }
        }
        __syncthreads();
        if (t < nb) {
            float fv = redv[0][t]; int fi = redi[0][t];
#pragma unroll
            for (int q = 1; q < 4; ++q) {
                float v = redv[q][t]; int ix = redi[q][t];
                if (v < fv || (v == fv && ix < fi)) { fv = v; fi = ix; }
            }
            idx_out[pxs[t]] = fi;
        }
    }
}

// -------- epilogue: gather + write quantize/idx + loss partials --------
__launch_bounds__(256)
__global__ void vq_epilogue(const float* __restrict__ x, const float* __restrict__ embed,
                            const int* __restrict__ idx_in, float* __restrict__ out_q,
                            float* __restrict__ out_idx, float* __restrict__ partials) {
    __shared__ int idxs[128];
    __shared__ float lred[4];
    const int t = threadIdx.x;
    const int n0 = blockIdx.x * 128;
    const int b = n0 >> 10;
    const int pix0 = n0 & 1023;
    const size_t xbase = (size_t)b * CDIM * HW + pix0;

    if (t < 128) {
        int iv = idx_in[n0 + t];
        idxs[t] = iv;
        out_idx[n0 + t] = (float)iv;
    }
    __syncthreads();

    const int pp = (t & 63) * 2;
    const int c0 = t >> 6;
    const int i0 = idxs[pp], i1 = idxs[pp + 1];
    float lsum = 0.f;
    for (int c = c0; c < CDIM; c += 4) {
        float2 xv = *(const float2*)&x[xbase + (size_t)c * HW + pp];
        float q0 = embed[c * KDIM + i0];
        float q1 = embed[c * KDIM + i1];
        *(float2*)&out_q[xbase + (size_t)c * HW + pp] = make_float2(q0, q1);
        float d0 = q0 - xv.x, d1 = q1 - xv.y;
        lsum = fmaf(d0, d0, lsum);
        lsum = fmaf(d1, d1, lsum);
    }
#pragma unroll
    for (int off = 32; off > 0; off >>= 1)
        lsum += __shfl_down(lsum, off, 64);
    if ((t & 63) == 0) lred[t >> 6] = lsum;
    __syncthreads();
    if (t == 0)
        partials[blockIdx.x] = (lred[0] + lred[1]) + (lred[2] + lred[3]);
}

__global__ void loss_kernel(const float* __restrict__ partials, float* __restrict__ out_loss) {
    __shared__ float s[256];
    s[threadIdx.x] = partials[threadIdx.x] + partials[threadIdx.x + 256];
    __syncthreads();
    for (int off = 128; off > 0; off >>= 1) {
        if (threadIdx.x < off) s[threadIdx.x] += s[threadIdx.x + off];
        __syncthreads();
    }
    if (threadIdx.x == 0)
        out_loss[0] = 1.25f * s[0] / 16777216.0f;
}

extern "C" void kernel_launch(void* const* d_in, const int* in_sizes, int n_in,
                              void* d_out, int out_size, void* d_ws, size_t ws_size,
                              hipStream_t stream) {
    const float* x     = (const float*)d_in[0];
    const float* embed = (const float*)d_in[1];
    float* out_q    = (float*)d_out;
    float* out_loss = out_q + (size_t)NPIX * CDIM;
    float* out_idx  = out_loss + 1;
    int*   idx_i32  = (int*)out_idx;

    // scratch inside out_q region (fully consumed before epilogue writes)
    short* e_hi     = (short*)out_q;              // 512 KB
    int*   worklist = (int*)(out_q + 131072);     // 256 KB

    float* ws       = (float*)d_ws;
    float* ee       = ws;                         // 1024 floats
    int*   wcount   = (int*)(ws + 1024);
    float* partials = ws + 1024 + 64;             // 512 floats

    ee_kernel<<<KDIM / 256, 256, 0, stream>>>(embed, ee);
    prep_e<<<128, 256, 0, stream>>>(embed, e_hi);
    hipMemsetAsync(wcount, 0, 4, stream);
    vq_gemm<<<NPIX / 256, 256, 0, stream>>>(x, e_hi, ee, idx_i32, worklist, wcount);
    vq_rescue<<<256, 256, 0, stream>>>(x, embed, ee, worklist, wcount, idx_i32);
    vq_epilogue<<<NPIX / 128, 256, 0, stream>>>(x, embed, idx_i32, out_q, out_idx, partials);
    loss_kernel<<<1, 256, 0, stream>>>(partials, out_loss);
}

// Round 4
// 186.569 us; speedup vs baseline: 2.4415x; 2.2680x over previous
//
#include <hip/hip_runtime.h>

#define CDIM 256
#define HW   1024
#define NPIX 65536
#define KDIM 1024
#define TAU  0.5f
#define RB   4

using bf16x8 = __attribute__((ext_vector_type(8))) short;
using f32x4  = __attribute__((ext_vector_type(4))) float;
typedef unsigned int u32;

static __device__ __forceinline__ unsigned short f2bf(float v) {
    union { float f; unsigned u; } a; a.f = v;
    unsigned u = a.u;
    u += 0x7fffu + ((u >> 16) & 1u);   // RTN
    return (unsigned short)(u >> 16);
}

static __device__ __forceinline__ void gload_lds16(const void* g, void* s) {
    __builtin_amdgcn_global_load_lds(
        (const __attribute__((address_space(1))) u32*)g,
        (__attribute__((address_space(3))) u32*)s,
        16, 0, 0);
}

// -------- ee[k] = sum_c embed[c][k]^2 (exact fp32) --------
__global__ void ee_kernel(const float* __restrict__ embed, float* __restrict__ ee) {
    int k = blockIdx.x * 256 + threadIdx.x;
    float s = 0.f;
#pragma unroll 8
    for (int c = 0; c < CDIM; ++c) {
        float v = embed[c * KDIM + k];
        s += v * v;
    }
    ee[k] = s;
}

// -------- bf16(-2*embed) in MFMA B-fragment order, chunk-contiguous --------
// frag f = ((nt*2+nh)*8 + ks)*4 + nf; lane l elem j:
//   B[k = ks*32 + (l>>4)*8 + j][n = nt*128 + (nh*4+nf)*16 + (l&15)]
__global__ void prep_e(const float* __restrict__ embed, short* __restrict__ e_hi) {
    int tid = blockIdx.x * 256 + threadIdx.x;   // 32768
    int l  = tid & 63;
    int f  = tid >> 6;            // 0..511
    int nf = f & 3;
    int ks = (f >> 2) & 7;
    int nh = (f >> 5) & 1;
    int nt = f >> 6;
    int n  = nt * 128 + (nh * 4 + nf) * 16 + (l & 15);
    int c0 = ks * 32 + (l >> 4) * 8;
    bf16x8 h8;
#pragma unroll
    for (int j = 0; j < 8; ++j)
        h8[j] = (short)f2bf(-2.0f * embed[(c0 + j) * KDIM + n]);
    *(bf16x8*)&e_hi[(size_t)tid * 8] = h8;
}

// -------- main: bf16 MFMA screen + argmin/min2 + near-tie flagging --------
__launch_bounds__(256, 1)
__global__ void vq_gemm(const float* __restrict__ x, const short* __restrict__ e_hi,
                        const float* __restrict__ ee, int* __restrict__ idx_out,
                        int* __restrict__ worklist, int* __restrict__ wcount) {
    __shared__ short Bs[2][16384];   // 2 x 32 KB chunks
    const int t  = threadIdx.x;
    const int l  = t & 63;
    const int w  = t >> 6;
    const int lr = l & 15;
    const int lg = l >> 4;
    const int px0 = blockIdx.x * 256 + w * 64;   // wave's 64 pixels
    const int b   = px0 >> 10;
    const int p0  = px0 & 1023;
    const float* xb = x + (size_t)b * CDIM * HW;

    // ---- load + convert A fragments (64 px x 256 ch -> 32 frags) ----
    bf16x8 a[4][8];
#pragma unroll
    for (int mf = 0; mf < 4; ++mf) {
#pragma unroll
        for (int ks = 0; ks < 8; ++ks) {
            const float* p = xb + (size_t)(ks * 32 + lg * 8) * HW + p0 + mf * 16 + lr;
            float v[8];
#pragma unroll
            for (int j = 0; j < 8; ++j) v[j] = p[(size_t)j * HW];
#pragma unroll
            for (int j = 0; j < 8; ++j) a[mf][ks][j] = (short)f2bf(v[j]);
        }
    }

    float minv[16], min2v[16];
    int   mini[16];
#pragma unroll
    for (int r = 0; r < 16; ++r) { minv[r] = 3.4e38f; min2v[r] = 3.4e38f; mini[r] = 0; }

    // prologue: stage chunk 0
    {
        const char* src = (const char*)e_hi + w * 8192 + l * 16;
        char* dst = (char*)&Bs[0][0] + w * 8192;
#pragma unroll
        for (int i = 0; i < 8; ++i)
            gload_lds16(src + i * 1024, dst + i * 1024);
    }
    __syncthreads();

    for (int ch = 0; ch < 16; ++ch) {
        const int cur = ch & 1;
        if (ch < 15) {   // issue next-chunk stage before compute (T3 minimum)
            const char* src = (const char*)e_hi + (size_t)(ch + 1) * 32768 + w * 8192 + l * 16;
            char* dst = (char*)&Bs[cur ^ 1][0] + w * 8192;
#pragma unroll
            for (int i = 0; i < 8; ++i)
                gload_lds16(src + i * 1024, dst + i * 1024);
        }

        f32x4 acc[4][4];
#pragma unroll
        for (int mf = 0; mf < 4; ++mf)
#pragma unroll
            for (int nf = 0; nf < 4; ++nf)
                acc[mf][nf] = (f32x4){0.f, 0.f, 0.f, 0.f};

#pragma unroll
        for (int ks = 0; ks < 8; ++ks) {
#pragma unroll
            for (int nf = 0; nf < 4; ++nf) {
                bf16x8 bh = *(const bf16x8*)&Bs[cur][((ks * 4 + nf) * 64 + l) * 8];
#pragma unroll
                for (int mf = 0; mf < 4; ++mf)
                    acc[mf][nf] = __builtin_amdgcn_mfma_f32_16x16x32_bf16(a[mf][ks], bh, acc[mf][nf], 0, 0, 0);
            }
        }

        // fold chunk into running (min, argmin, second-min)
#pragma unroll
        for (int nf = 0; nf < 4; ++nf) {
            const int kg = ch * 64 + nf * 16 + lr;
            const float eev = ee[kg];
#pragma unroll
            for (int mf = 0; mf < 4; ++mf)
#pragma unroll
                for (int j = 0; j < 4; ++j) {
                    const int r = mf * 4 + j;
                    float m = acc[mf][nf][j] + eev;
                    bool lt = m < minv[r];
                    float sec = lt ? minv[r] : m;
                    minv[r] = lt ? m : minv[r];
                    mini[r] = lt ? kg : mini[r];
                    min2v[r] = fminf(min2v[r], sec);
                }
        }
        __syncthreads();   // drains stage vmcnt + protects buffer swap
    }

    // ---- reduce across the 16 lanes sharing each pixel row ----
#pragma unroll
    for (int r = 0; r < 16; ++r) {
        float v1 = minv[r]; int i1 = mini[r]; float v2 = min2v[r];
#pragma unroll
        for (int mask = 1; mask < 16; mask <<= 1) {
            float ov1 = __shfl_xor(v1, mask, 64);
            int   oi1 = __shfl_xor(i1, mask, 64);
            float ov2 = __shfl_xor(v2, mask, 64);
            float vmax = fmaxf(v1, ov1);
            v2 = fminf(fminf(v2, ov2), vmax);
            bool take = (ov1 < v1) || (ov1 == v1 && oi1 < i1);
            v1 = take ? ov1 : v1;
            i1 = take ? oi1 : i1;
        }
        if (lr == 0) {
            int px = px0 + (r >> 2) * 16 + lg * 4 + (r & 3);
            idx_out[px] = i1;
            if (v2 - v1 < TAU) {
                int pos = atomicAdd(wcount, 1);
                worklist[pos] = px;
            }
        }
    }
}

// -------- exact fp32 rescore: RB px/block, thread t owns codes 4t..4t+3 --------
__launch_bounds__(256)
__global__ void vq_rescue(const float* __restrict__ x, const float* __restrict__ embed,
                          const float* __restrict__ ee,
                          const int* __restrict__ worklist, const int* __restrict__ wcount,
                          int* __restrict__ idx_out) {
    __shared__ float xs[RB][CDIM];
    __shared__ int   pxs[RB];
    __shared__ float redv[4][RB];
    __shared__ int   redi[4][RB];
    const int t  = threadIdx.x;
    const int wv = t >> 6, ln = t & 63;
    const int cnt = *wcount;
    for (int base = blockIdx.x * RB; base < cnt; base += gridDim.x * RB) {
        const int nb = min(RB, cnt - base);
        __syncthreads();
        if (t < RB) pxs[t] = worklist[base + (t < nb ? t : nb - 1)];
        __syncthreads();
#pragma unroll
        for (int i = 0; i < RB; ++i) {
            int gn = pxs[i];
            xs[i][t] = x[(size_t)(gn >> 10) * CDIM * HW + (size_t)t * HW + (gn & 1023)];
        }
        __syncthreads();

        float4 acc[RB];
#pragma unroll
        for (int i = 0; i < RB; ++i) acc[i] = make_float4(0.f, 0.f, 0.f, 0.f);
#pragma unroll 4
        for (int c = 0; c < CDIM; ++c) {
            float4 ev = *(const float4*)&embed[c * KDIM + t * 4];
#pragma unroll
            for (int i = 0; i < RB; ++i) {
                float xv = xs[i][c];
                acc[i].x = fmaf(xv, ev.x, acc[i].x);
                acc[i].y = fmaf(xv, ev.y, acc[i].y);
                acc[i].z = fmaf(xv, ev.z, acc[i].z);
                acc[i].w = fmaf(xv, ev.w, acc[i].w);
            }
        }
        const float4 eev = *(const float4*)&ee[t * 4];
#pragma unroll
        for (int i = 0; i < RB; ++i) {
            float d0 = fmaf(-2.f, acc[i].x, eev.x);
            float d1 = fmaf(-2.f, acc[i].y, eev.y);
            float d2 = fmaf(-2.f, acc[i].z, eev.z);
            float d3 = fmaf(-2.f, acc[i].w, eev.w);
            float v = d0; int ix = t * 4;
            if (d1 < v) { v = d1; ix = t * 4 + 1; }
            if (d2 < v) { v = d2; ix = t * 4 + 2; }
            if (d3 < v) { v = d3; ix = t * 4 + 3; }
#pragma unroll
            for (int mask = 1; mask < 64; mask <<= 1) {
                float ov = __shfl_xor(v, mask, 64);
                int   oi = __shfl_xor(ix, mask, 64);
                bool take = (ov < v) || (ov == v && oi < ix);
                v = take ? ov : v; ix = take ? oi : ix;
            }
            if (ln == 0) { redv[wv][i] = v; redi[wv][i] = ix; }
        }
        __syncthreads();
        if (t < nb) {
            float fv = redv[0][t]; int fi = redi[0][t];
#pragma unroll
            for (int q = 1; q < 4; ++q) {
                float v = redv[q][t]; int ix = redi[q][t];
                if (v < fv || (v == fv && ix < fi)) { fv = v; fi = ix; }
            }
            idx_out[pxs[t]] = fi;
        }
    }
}

// -------- epilogue: gather + write quantize/idx + loss partials --------
__launch_bounds__(256)
__global__ void vq_epilogue(const float* __restrict__ x, const float* __restrict__ embed,
                            const int* __restrict__ idx_in, float* __restrict__ out_q,
                            float* __restrict__ out_idx, float* __restrict__ partials) {
    __shared__ int idxs[128];
    __shared__ float lred[4];
    const int t = threadIdx.x;
    const int n0 = blockIdx.x * 128;
    const int b = n0 >> 10;
    const int pix0 = n0 & 1023;
    const size_t xbase = (size_t)b * CDIM * HW + pix0;

    if (t < 128) {
        int iv = idx_in[n0 + t];
        idxs[t] = iv;
        out_idx[n0 + t] = (float)iv;
    }
    __syncthreads();

    const int pp = (t & 63) * 2;
    const int c0 = t >> 6;
    const int i0 = idxs[pp], i1 = idxs[pp + 1];
    float lsum = 0.f;
    for (int c = c0; c < CDIM; c += 4) {
        float2 xv = *(const float2*)&x[xbase + (size_t)c * HW + pp];
        float q0 = embed[c * KDIM + i0];
        float q1 = embed[c * KDIM + i1];
        *(float2*)&out_q[xbase + (size_t)c * HW + pp] = make_float2(q0, q1);
        float d0 = q0 - xv.x, d1 = q1 - xv.y;
        lsum = fmaf(d0, d0, lsum);
        lsum = fmaf(d1, d1, lsum);
    }
#pragma unroll
    for (int off = 32; off > 0; off >>= 1)
        lsum += __shfl_down(lsum, off, 64);
    if ((t & 63) == 0) lred[t >> 6] = lsum;
    __syncthreads();
    if (t == 0)
        partials[blockIdx.x] = (lred[0] + lred[1]) + (lred[2] + lred[3]);
}

__global__ void loss_kernel(const float* __restrict__ partials, float* __restrict__ out_loss) {
    __shared__ float s[256];
    s[threadIdx.x] = partials[threadIdx.x] + partials[threadIdx.x + 256];
    __syncthreads();
    for (int off = 128; off > 0; off >>= 1) {
        if (threadIdx.x < off) s[threadIdx.x] += s[threadIdx.x + off];
        __syncthreads();
    }
    if (threadIdx.x == 0)
        out_loss[0] = 1.25f * s[0] / 16777216.0f;
}

extern "C" void kernel_launch(void* const* d_in, const int* in_sizes, int n_in,
                              void* d_out, int out_size, void* d_ws, size_t ws_size,
                              hipStream_t stream) {
    const float* x     = (const float*)d_in[0];
    const float* embed = (const float*)d_in[1];
    float* out_q    = (float*)d_out;
    float* out_loss = out_q + (size_t)NPIX * CDIM;
    float* out_idx  = out_loss + 1;
    int*   idx_i32  = (int*)out_idx;

    // scratch inside out_q region (fully consumed before epilogue writes)
    short* e_hi     = (short*)out_q;              // 512 KB
    int*   worklist = (int*)(out_q + 131072);     // 256 KB

    float* ws       = (float*)d_ws;
    float* ee       = ws;                         // 1024 floats
    int*   wcount   = (int*)(ws + 1024);
    float* partials = ws + 1024 + 64;             // 512 floats

    ee_kernel<<<KDIM / 256, 256, 0, stream>>>(embed, ee);
    prep_e<<<128, 256, 0, stream>>>(embed, e_hi);
    hipMemsetAsync(wcount, 0, 4, stream);
    vq_gemm<<<NPIX / 256, 256, 0, stream>>>(x, e_hi, ee, idx_i32, worklist, wcount);
    vq_rescue<<<1024, 256, 0, stream>>>(x, embed, ee, worklist, wcount, idx_i32);
    vq_epilogue<<<NPIX / 128, 256, 0, stream>>>(x, embed, idx_i32, out_q, out_idx, partials);
    loss_kernel<<<1, 256, 0, stream>>>(partials, out_loss);
}